// Round 8
// baseline (509.379 us; speedup 1.0000x reference)
//
#include <hip/hip_runtime.h>
#include <math.h>

#define NM   50
#define NB   128
#define NL   3
#define NCLS 10

#define PI_D        3.14159265358979323846264338327950288
#define TWO_PI_D    6.28318530717958647692528676655900577
#define INV_2PI_D   0.159154943091895335768883763372514362
#define LAMBDA_D    5.32e-07
#define DIST_D      0.035
#define PLD_D       (PI_D * LAMBDA_D * DIST_D)

// Output scale: reference applies (1/4096) per ifft2 (x3 layers) which we drop
// (exact power of 2), and e^{ikD} global phase per layer (killed by |.|^2).
// Intensity thus carries 2^72; fold 2^-72 / NM into the FC accumulation.
#define OUT_SCALE 4.2351647362715017e-24f   // (1/50) * 2^-72

typedef float f2 __attribute__((ext_vector_type(2)));

__device__ __forceinline__ f2 mkf2(float a, float b) { f2 r; r.x = a; r.y = b; return r; }

// Unified LDS swizzle (R4/R7-proven): element (r,c) at r*64 + (c ^ ((r&3)<<2) ^ ((c>>4)&3)).
__device__ __forceinline__ int sw(int r, int c) {
    return r * 64 + (c ^ (((r & 3) << 2) ^ ((c >> 4) & 3)));
}
// intensity-buffer swizzle (write natural-per-quad, read row-contiguous)
#define QS(r) ((((r) & 15)) << 1)

__device__ __forceinline__ constexpr int rev4(int i) {
    return ((i & 1) << 3) | ((i & 2) << 1) | ((i & 4) >> 1) | ((i & 8) >> 3);
}

__device__ __forceinline__ float dppx1(float v) {  // lane ^ 1 within quad
    return __int_as_float(__builtin_amdgcn_mov_dpp(__float_as_int(v), 0xB1, 0xF, 0xF, true));
}
__device__ __forceinline__ float dppx2(float v) {  // lane ^ 2 within quad
    return __int_as_float(__builtin_amdgcn_mov_dpp(__float_as_int(v), 0x4E, 0xF, 0xF, true));
}

// ---- complex primitives as f2 vector expressions (compiler forms VOP3P) ----
__device__ __forceinline__ f2 cmul(f2 a, f2 w) {          // a * w
    return a * w.x + a.yx * mkf2(-w.y, w.y);
}
__device__ __forceinline__ f2 cmulc(f2 a, f2 w) {         // a * conj(w)
    return a * w.x + a.yx * mkf2(w.y, -w.y);
}

__device__ __forceinline__ constexpr float c16t(int tw) {
    return (tw == 1) ? 0.923879532511286756f : (tw == 2) ? 0.707106781186547524f :
           (tw == 3) ? 0.382683432365089772f : (tw == 5) ? -0.382683432365089772f :
           (tw == 6) ? -0.707106781186547524f : (tw == 7) ? -0.923879532511286756f : 1.0f;
}
__device__ __forceinline__ constexpr float s16t(int tw) {
    return (tw == 1) ? 0.382683432365089772f : (tw == 2) ? 0.707106781186547524f :
           (tw == 3) ? 0.923879532511286756f : (tw == 5) ? 0.923879532511286756f :
           (tw == 6) ? 0.707106781186547524f : (tw == 7) ? 0.382683432365089772f : 0.0f;
}

// in-place DIF-16, natural in, bit-reversed out (pos i holds X[rev4(i)]), e^{-i}.
__device__ __forceinline__ void dif16_fwd(f2* x) {
#pragma unroll
    for (int len = 8; len >= 1; len >>= 1) {
#pragma unroll
        for (int base = 0; base < 16; base += 2 * len) {
#pragma unroll
            for (int j = 0; j < len; j++) {
                const int i0 = base + j, i1 = i0 + len;
                const int tw = j * (8 / len);
                f2 a = x[i0], b = x[i1];
                x[i0] = a + b;
                f2 d = a - b;
                if (tw == 0)      { x[i1] = d; }
                else if (tw == 4) { x[i1] = mkf2(d.y, -d.x); }              // * (-i)
                else {
                    const float c = c16t(tw), s = s16t(tw);
                    x[i1] = d * c + d.yx * mkf2(s, -s);
                }
            }
        }
    }
}

// in-place DIT-16, bit-reversed in, natural out, e^{+i}, unscaled.
__device__ __forceinline__ void dit16_inv(f2* x) {
#pragma unroll
    for (int len = 1; len <= 8; len <<= 1) {
#pragma unroll
        for (int base = 0; base < 16; base += 2 * len) {
#pragma unroll
            for (int j = 0; j < len; j++) {
                const int i0 = base + j, i1 = i0 + len;
                const int tw = j * (8 / len);
                f2 a = x[i0], b = x[i1];
                if (tw == 4)      { b = mkf2(-b.y, b.x); }                  // * (+i)
                else if (tw != 0) {
                    const float c = c16t(tw), s = s16t(tw);
                    b = b * c + b.yx * mkf2(-s, s);
                }
                x[i0] = a + b;
                x[i1] = a - b;
            }
        }
    }
}

// forward cross-quad 4-pt DFT: stage xor2, lane3 *(-i), stage xor1.
__device__ __forceinline__ void quad_fwd(f2* x, float s1, float s2, bool l3) {
#pragma unroll
    for (int i = 0; i < 16; i++) {
        f2 p = mkf2(dppx2(x[i].x), dppx2(x[i].y));
        f2 r = x[i] * s2 + p;
        f2 r2 = l3 ? mkf2(r.y, -r.x) : r;
        f2 q = mkf2(dppx1(r2.x), dppx1(r2.y));
        x[i] = r2 * s1 + q;
    }
}

// inverse cross-quad 4-pt DFT: stage xor1, lane3 *(+i), stage xor2 (unscaled).
__device__ __forceinline__ void quad_inv(f2* x, float s1, float s2, bool l3) {
#pragma unroll
    for (int i = 0; i < 16; i++) {
        f2 p = mkf2(dppx1(x[i].x), dppx1(x[i].y));
        f2 r = x[i] * s1 + p;
        f2 r2 = l3 ? mkf2(-r.y, r.x) : r;
        f2 q = mkf2(dppx2(r2.x), dppx2(r2.y));
        x[i] = r2 * s2 + q;
    }
}

// 64-pt forward: reg i, lane t -> X[rev4(i)+16*sig]; twiddles from f2 LDS table.
__device__ __forceinline__ void fwd64(f2* x, const f2* w64t, int t, float s1, float s2, bool l3) {
    dif16_fwd(x);
#pragma unroll
    for (int i = 1; i < 16; i++) x[i] = cmulc(x[i], w64t[t * rev4(i)]);
    quad_fwd(x, s1, s2, l3);
}
__device__ __forceinline__ void inv64(f2* x, const f2* w64t, int t, float s1, float s2, bool l3) {
    quad_inv(x, s1, s2, l3);
#pragma unroll
    for (int i = 1; i < 16; i++) x[i] = cmul(x[i], w64t[t * rev4(i)]);
    dit16_inv(x);
}

// ---------- pre-kernel: phase cos/sin in per-thread-contiguous layout ----------
__global__ __launch_bounds__(256) void donn_tables(
    const float* __restrict__ phase, f2* __restrict__ ws)
{
    const int id = blockIdx.x * 256 + threadIdx.x;   // 48*256 = 12288 = NL*4096
    const int l = id >> 12, rr = id & 4095;
    const int tidm = rr >> 4, j = rr & 15;
    const int g = tidm >> 2, t = tidm & 3;
    float ph = phase[l * 4096 + g * 64 + 4 * j + t];
    float s, c;
    sincosf(ph, &s, &c);
    ws[id] = mkf2(c, s);
}

// ---------- main kernel ----------
__global__ __launch_bounds__(256) void donn_main(
    const float* __restrict__ x,
    const float* __restrict__ sre,
    const float* __restrict__ sim,
    const f2* __restrict__ ws,
    const float* __restrict__ fcw,
    const float* __restrict__ fcb,
    float* __restrict__ out)
{
    __shared__ f2 xb2[4096];
    __shared__ f2 w64t[64];
    __shared__ f2 hx2[64];

    const int tid = threadIdx.x;
    const int bid = blockIdx.x;
    const int b = bid & (NB - 1);
    const int m = bid >> 7;
    const int g = tid >> 2, t = tid & 3;
    const int sig = ((t & 1) << 1) | (t >> 1);
    const bool l3 = (t == 3);
    const float s1 = (t & 1) ? -1.f : 1.f;
    const float s2 = (t & 2) ? -1.f : 1.f;

    if (tid < 64) {
        float s, c;
        __sincosf((float)tid * (float)(TWO_PI_D / 64.0), &s, &c);
        w64t[tid] = mkf2(c, s);
        // Hx[k] = exp(-i*pi*lambda*D*f_k^2), f_k = signed(k)*15625; f64 range-reduce.
        double f = (double)((tid < 32) ? tid : tid - 64) * 15625.0;
        double phd = -PLD_D * f * f;
        double r1 = phd - TWO_PI_D * rint(phd * INV_2PI_D);
        hx2[tid] = mkf2(cosf((float)r1), sinf((float)r1));
        // NOTE: Hy = Hx * e^{ikD} / 4096 -- e^{ikD} is a global phase (killed by
        // |.|^2), 1/4096 is folded into OUT_SCALE. So hx2 serves both mults.
    }

    // stage field = x * screen: coalesced float4 loads -> row g of xb2 (quad-
    // local: row g written and read only by threads (g,0..3), same wave).
    f2 X[16];
    {
        const float4* xp = (const float4*)(x   + (size_t)b * 4096 + tid * 16);
        const float4* rp = (const float4*)(sre + (size_t)m * 4096 + tid * 16);
        const float4* ip = (const float4*)(sim + (size_t)m * 4096 + tid * 16);
#pragma unroll
        for (int a = 0; a < 4; a++) {
            float4 xv = xp[a], rv = rp[a], iv = ip[a];
            xb2[sw(g, 16 * t + 4 * a + 0)] = mkf2(xv.x * rv.x, xv.x * iv.x);
            xb2[sw(g, 16 * t + 4 * a + 1)] = mkf2(xv.y * rv.y, xv.y * iv.y);
            xb2[sw(g, 16 * t + 4 * a + 2)] = mkf2(xv.z * rv.z, xv.z * iv.z);
            xb2[sw(g, 16 * t + 4 * a + 3)] = mkf2(xv.w * rv.w, xv.w * iv.w);
        }
#pragma unroll
        for (int j = 0; j < 16; j++)
            X[j] = xb2[sw(g, 4 * j + t)];
    }
    __syncthreads();   // publishes w64t/hx2 (staging was quad-local)

#pragma unroll 1
    for (int l = 0; l < NL; l++) {
        // multiply exp(i*phase_l): precomputed cos/sin, per-thread-contiguous
        const float4* csp = (const float4*)(ws + ((l * 256 + tid) << 4));
#pragma unroll
        for (int q = 0; q < 8; q++) {
            float4 c4 = csp[q];
            X[2 * q]     = cmul(X[2 * q],     mkf2(c4.x, c4.y));
            X[2 * q + 1] = cmul(X[2 * q + 1], mkf2(c4.z, c4.w));
        }
        // FFT along x, * Hx
        fwd64(X, w64t, t, s1, s2, l3);
#pragma unroll
        for (int i = 0; i < 16; i++) {
            const int kk = rev4(i) + 16 * sig;
            X[i] = cmul(X[i], hx2[kk]);
        }
        // transpose #1 write (cells (g,kk) == own T2-read set of prev layer and
        // thread-unique -> no pre-barrier; b64 ops)
#pragma unroll
        for (int i = 0; i < 16; i++) {
            const int kk = rev4(i) + 16 * sig;
            xb2[sw(g, kk)] = X[i];
        }
        __syncthreads();
#pragma unroll
        for (int j = 0; j < 16; j++)
            X[j] = xb2[sw(4 * j + t, g)];
        // FFT along y, * Hx (== Hy up to global phase & folded 2^-12 scale),
        // inverse FFT along y -- all in regs
        fwd64(X, w64t, t, s1, s2, l3);
#pragma unroll
        for (int i = 0; i < 16; i++) {
            const int kk = rev4(i) + 16 * sig;
            X[i] = cmul(X[i], hx2[kk]);
        }
        inv64(X, w64t, t, s1, s2, l3);
        // transpose #2 write (cells (n,g) == own T1-read set -> no pre-barrier)
#pragma unroll
        for (int j = 0; j < 16; j++)
            xb2[sw(4 * j + t, g)] = X[j];
        __syncthreads();
#pragma unroll
        for (int i = 0; i < 16; i++) {
            const int kk = rev4(i) + 16 * sig;
            X[i] = xb2[sw(g, kk)];
        }
        // inverse FFT along x -> natural spatial order for next layer
        inv64(X, w64t, t, s1, s2, l3);
    }

    // intensity -> float view of xb2 (QS layout). Barrier first: float rows
    // alias f2 rows that OTHER waves just T2-read.
    __syncthreads();
    float* xbf = (float*)xb2;
    const int qsg = QS(g);
#pragma unroll
    for (int j = 0; j < 16; j++) {
        const int c0 = 4 * j + t;
        xbf[g * 64 + (c0 ^ qsg)] = fmaf(X[j].x, X[j].x, X[j].y * X[j].y);
    }
    __syncthreads();   // pre-FC barrier (FC reads cross rows)

    float part[NCLS];
#pragma unroll
    for (int c2 = 0; c2 < NCLS; c2++) part[c2] = 0.f;
#pragma unroll
    for (int i = 0; i < 16; i++) {
        const int e = i * 256 + tid;
        const int r = e >> 6, c = e & 63;
        const float iv = xbf[r * 64 + (c ^ QS(r))];
        const float* wcol = fcw + e;
#pragma unroll
        for (int c2 = 0; c2 < NCLS; c2++)
            part[c2] = fmaf(iv, wcol[(size_t)c2 * 4096], part[c2]);
    }
#pragma unroll
    for (int c2 = 0; c2 < NCLS; c2++) {
        float v = part[c2];
#pragma unroll
        for (int off = 32; off >= 1; off >>= 1) v += __shfl_down(v, off);
        if ((tid & 63) == 0) atomicAdd(&out[b * NCLS + c2], v * OUT_SCALE);
    }
    if (m == 0 && tid < NCLS) atomicAdd(&out[b * NCLS + tid], fcb[tid]);
}

extern "C" void kernel_launch(void* const* d_in, const int* in_sizes, int n_in,
                              void* d_out, int out_size, void* d_ws, size_t ws_size,
                              hipStream_t stream) {
    const float* x   = (const float*)d_in[0];
    const float* sre = (const float*)d_in[1];
    const float* sim = (const float*)d_in[2];
    const float* ph  = (const float*)d_in[3];
    const float* fcw = (const float*)d_in[4];
    const float* fcb = (const float*)d_in[5];
    float* out = (float*)d_out;
    f2* ws = (f2*)d_ws;   // NL*4096 f2 = 96 KB phase cos/sin tables

    hipMemsetAsync(out, 0, (size_t)(NB * NCLS) * sizeof(float), stream);
    donn_tables<<<48, 256, 0, stream>>>(ph, ws);
    donn_main<<<NM * NB, 256, 0, stream>>>(x, sre, sim, ws, fcw, fcb, out);
}

// Round 9
// 321.659 us; speedup vs baseline: 1.5836x; 1.5836x over previous
//
#include <hip/hip_runtime.h>
#include <math.h>

#define NM   50
#define NB   128
#define NL   3
#define NCLS 10

#define PI_D        3.14159265358979323846264338327950288
#define TWO_PI_D    6.28318530717958647692528676655900577
#define INV_2PI_D   0.159154943091895335768883763372514362
#define LAMBDA_D    5.32e-07
#define DIST_D      0.035
#define PLD_D       (PI_D * LAMBDA_D * DIST_D)

// Reference per layer: field = ifft2(fft2(field * e^{i phase}) * H),
// H = e^{ikD} * Hx[fx] * Hy[fy], Hx=Hy=exp(-i pi lam D f^2), ifft2 has 1/4096.
// We drop e^{ikD} (global phase, killed by |.|^2) and the 1/4096 (exact 2^-12),
// so both H-multiplies use the same hx2 table and the field carries 4096^3
// after 3 layers -> intensity carries 2^72. Fold 2^-72 and the 1/NM Monte-
// Carlo average into one FC constant:
#define OUT_SCALE 4.2351647362715017e-24f   // (1/50) * 2^-72

typedef float f2 __attribute__((ext_vector_type(2)));

__device__ __forceinline__ f2 mkf2(float a, float b) { f2 r; r.x = a; r.y = b; return r; }

// Unified LDS swizzle (R4/R7-proven): element (r,c) at r*64 + (c ^ ((r&3)<<2) ^ ((c>>4)&3)).
__device__ __forceinline__ int sw(int r, int c) {
    return r * 64 + (c ^ (((r & 3) << 2) ^ ((c >> 4) & 3)));
}
// intensity-buffer swizzle (write natural-per-quad, read row-contiguous)
#define QS(r) ((((r) & 15)) << 1)

__device__ __forceinline__ constexpr int rev4(int i) {
    return ((i & 1) << 3) | ((i & 2) << 1) | ((i & 4) >> 1) | ((i & 8) >> 3);
}

__device__ __forceinline__ float dppx1(float v) {  // lane ^ 1 within quad
    return __int_as_float(__builtin_amdgcn_mov_dpp(__float_as_int(v), 0xB1, 0xF, 0xF, true));
}
__device__ __forceinline__ float dppx2(float v) {  // lane ^ 2 within quad
    return __int_as_float(__builtin_amdgcn_mov_dpp(__float_as_int(v), 0x4E, 0xF, 0xF, true));
}

// ---- complex primitives as f2 vector expressions (compiler forms VOP3P) ----
__device__ __forceinline__ f2 cmul(f2 a, f2 w) {          // a * w
    return a * w.x + a.yx * mkf2(-w.y, w.y);
}
__device__ __forceinline__ f2 cmulc(f2 a, f2 w) {         // a * conj(w)
    return a * w.x + a.yx * mkf2(w.y, -w.y);
}

__device__ __forceinline__ constexpr float c16t(int tw) {
    return (tw == 1) ? 0.923879532511286756f : (tw == 2) ? 0.707106781186547524f :
           (tw == 3) ? 0.382683432365089772f : (tw == 5) ? -0.382683432365089772f :
           (tw == 6) ? -0.707106781186547524f : (tw == 7) ? -0.923879532511286756f : 1.0f;
}
__device__ __forceinline__ constexpr float s16t(int tw) {
    return (tw == 1) ? 0.382683432365089772f : (tw == 2) ? 0.707106781186547524f :
           (tw == 3) ? 0.923879532511286756f : (tw == 5) ? 0.923879532511286756f :
           (tw == 6) ? 0.707106781186547524f : (tw == 7) ? 0.382683432365089772f : 0.0f;
}

// in-place DIF-16, natural in, bit-reversed out (pos i holds X[rev4(i)]), e^{-i}.
__device__ __forceinline__ void dif16_fwd(f2* x) {
#pragma unroll
    for (int len = 8; len >= 1; len >>= 1) {
#pragma unroll
        for (int base = 0; base < 16; base += 2 * len) {
#pragma unroll
            for (int j = 0; j < len; j++) {
                const int i0 = base + j, i1 = i0 + len;
                const int tw = j * (8 / len);
                f2 a = x[i0], b = x[i1];
                x[i0] = a + b;
                f2 d = a - b;
                if (tw == 0)      { x[i1] = d; }
                else if (tw == 4) { x[i1] = mkf2(d.y, -d.x); }              // * (-i)
                else {
                    const float c = c16t(tw), s = s16t(tw);
                    x[i1] = d * c + d.yx * mkf2(s, -s);
                }
            }
        }
    }
}

// in-place DIT-16, bit-reversed in, natural out, e^{+i}, unscaled.
__device__ __forceinline__ void dit16_inv(f2* x) {
#pragma unroll
    for (int len = 1; len <= 8; len <<= 1) {
#pragma unroll
        for (int base = 0; base < 16; base += 2 * len) {
#pragma unroll
            for (int j = 0; j < len; j++) {
                const int i0 = base + j, i1 = i0 + len;
                const int tw = j * (8 / len);
                f2 a = x[i0], b = x[i1];
                if (tw == 4)      { b = mkf2(-b.y, b.x); }                  // * (+i)
                else if (tw != 0) {
                    const float c = c16t(tw), s = s16t(tw);
                    b = b * c + b.yx * mkf2(-s, s);
                }
                x[i0] = a + b;
                x[i1] = a - b;
            }
        }
    }
}

// forward cross-quad 4-pt DFT: stage xor2, lane3 *(-i), stage xor1.
__device__ __forceinline__ void quad_fwd(f2* x, float s1, float s2, bool l3) {
#pragma unroll
    for (int i = 0; i < 16; i++) {
        f2 p = mkf2(dppx2(x[i].x), dppx2(x[i].y));
        f2 r = x[i] * s2 + p;
        f2 r2 = l3 ? mkf2(r.y, -r.x) : r;
        f2 q = mkf2(dppx1(r2.x), dppx1(r2.y));
        x[i] = r2 * s1 + q;
    }
}

// inverse cross-quad 4-pt DFT: stage xor1, lane3 *(+i), stage xor2 (unscaled).
__device__ __forceinline__ void quad_inv(f2* x, float s1, float s2, bool l3) {
#pragma unroll
    for (int i = 0; i < 16; i++) {
        f2 p = mkf2(dppx1(x[i].x), dppx1(x[i].y));
        f2 r = x[i] * s1 + p;
        f2 r2 = l3 ? mkf2(-r.y, r.x) : r;
        f2 q = mkf2(dppx2(r2.x), dppx2(r2.y));
        x[i] = r2 * s2 + q;
    }
}

// 64-pt forward: reg i, lane t -> X[rev4(i)+16*sig]; twiddles from f2 LDS table.
__device__ __forceinline__ void fwd64(f2* x, const f2* w64t, int t, float s1, float s2, bool l3) {
    dif16_fwd(x);
#pragma unroll
    for (int i = 1; i < 16; i++) x[i] = cmulc(x[i], w64t[t * rev4(i)]);
    quad_fwd(x, s1, s2, l3);
}
__device__ __forceinline__ void inv64(f2* x, const f2* w64t, int t, float s1, float s2, bool l3) {
    quad_inv(x, s1, s2, l3);
#pragma unroll
    for (int i = 1; i < 16; i++) x[i] = cmul(x[i], w64t[t * rev4(i)]);
    dit16_inv(x);
}

__global__ __launch_bounds__(256) void donn_main(
    const float* __restrict__ x,
    const float* __restrict__ sre,
    const float* __restrict__ sim,
    const float* __restrict__ phase,
    const float* __restrict__ fcw,
    const float* __restrict__ fcb,
    float* __restrict__ out)
{
    __shared__ f2 xb2[4096];
    __shared__ f2 w64t[64];
    __shared__ f2 hx2[64];

    const int tid = threadIdx.x;
    const int bid = blockIdx.x;
    const int b = bid & (NB - 1);
    const int m = bid >> 7;
    const int g = tid >> 2, t = tid & 3;
    const int sig = ((t & 1) << 1) | (t >> 1);
    const bool l3 = (t == 3);
    const float s1 = (t & 1) ? -1.f : 1.f;
    const float s2 = (t & 2) ? -1.f : 1.f;

    if (tid < 64) {
        float s, c;
        __sincosf((float)tid * (float)(TWO_PI_D / 64.0), &s, &c);
        w64t[tid] = mkf2(c, s);
        // Hx[k] = exp(-i*pi*lambda*D*f_k^2), f_k = signed(k)*15625; f64 range-reduce.
        double f = (double)((tid < 32) ? tid : tid - 64) * 15625.0;
        double phd = -PLD_D * f * f;
        double r1 = phd - TWO_PI_D * rint(phd * INV_2PI_D);
        hx2[tid] = mkf2(cosf((float)r1), sinf((float)r1));
        // Hy = Hx * e^{ikD} * 2^-12: global phase + exact scale, folded into
        // OUT_SCALE -> hx2 serves both frequency-domain multiplies.
    }

    // stage field = x * screen straight into registers (cols 4j+t of row g)
    f2 X[16];
    {
        const float* xb = x   + b * 4096 + g * 64 + t;
        const float* sr = sre + m * 4096 + g * 64 + t;
        const float* si = sim + m * 4096 + g * 64 + t;
#pragma unroll
        for (int j = 0; j < 16; j++) {
            float xv = xb[4 * j];
            X[j].x = xv * sr[4 * j];
            X[j].y = xv * si[4 * j];
        }
    }
    __syncthreads();   // publishes w64t/hx2

#pragma unroll 1
    for (int l = 0; l < NL; l++) {
        __builtin_amdgcn_s_setprio(1);
        // multiply exp(i*phase_l) (natural order in regs)
        const float* ph = phase + l * 4096 + g * 64 + t;
#pragma unroll
        for (int j = 0; j < 16; j++) {
            float s, c;
            __sincosf(ph[4 * j], &s, &c);
            X[j] = cmul(X[j], mkf2(c, s));
        }
        // FFT along x, * Hx
        fwd64(X, w64t, t, s1, s2, l3);
#pragma unroll
        for (int i = 0; i < 16; i++) {
            const int kk = rev4(i) + 16 * sig;
            X[i] = cmul(X[i], hx2[kk]);
        }
        __builtin_amdgcn_s_setprio(0);
        // transpose #1 write (cells (g,kk) == own T2-read set of prev layer and
        // thread-unique -> no pre-barrier; b64 ops)
#pragma unroll
        for (int i = 0; i < 16; i++) {
            const int kk = rev4(i) + 16 * sig;
            xb2[sw(g, kk)] = X[i];
        }
        __syncthreads();
#pragma unroll
        for (int j = 0; j < 16; j++)
            X[j] = xb2[sw(4 * j + t, g)];
        __builtin_amdgcn_s_setprio(1);
        // FFT along y, * Hx (== Hy up to global phase & folded 2^-12 scale),
        // inverse FFT along y -- all in regs
        fwd64(X, w64t, t, s1, s2, l3);
#pragma unroll
        for (int i = 0; i < 16; i++) {
            const int kk = rev4(i) + 16 * sig;
            X[i] = cmul(X[i], hx2[kk]);
        }
        inv64(X, w64t, t, s1, s2, l3);
        __builtin_amdgcn_s_setprio(0);
        // transpose #2 write (cells (n,g) == own T1-read set -> no pre-barrier)
#pragma unroll
        for (int j = 0; j < 16; j++)
            xb2[sw(4 * j + t, g)] = X[j];
        __syncthreads();
#pragma unroll
        for (int i = 0; i < 16; i++) {
            const int kk = rev4(i) + 16 * sig;
            X[i] = xb2[sw(g, kk)];
        }
        __builtin_amdgcn_s_setprio(1);
        // inverse FFT along x -> natural spatial order for next layer
        inv64(X, w64t, t, s1, s2, l3);
        __builtin_amdgcn_s_setprio(0);
    }

    // intensity -> float view of xb2 (QS layout). Barrier first: float rows
    // alias f2 rows that OTHER waves just T2-read.
    __syncthreads();
    float* xbf = (float*)xb2;
    const int qsg = QS(g);
#pragma unroll
    for (int j = 0; j < 16; j++) {
        const int c0 = 4 * j + t;
        xbf[g * 64 + (c0 ^ qsg)] = fmaf(X[j].x, X[j].x, X[j].y * X[j].y);
    }
    __syncthreads();   // pre-FC barrier (FC reads cross rows)

    float ivl[16];
#pragma unroll
    for (int i = 0; i < 16; i++) {
        const int e = i * 256 + tid;
        const int r = e >> 6, c = e & 63;
        ivl[i] = xbf[r * 64 + (c ^ QS(r))];
    }
    float part[NCLS];
#pragma unroll
    for (int c2 = 0; c2 < NCLS; c2++) part[c2] = 0.f;
#pragma unroll
    for (int c2 = 0; c2 < NCLS; c2++) {
        const float* wrow = fcw + c2 * 4096 + tid;
#pragma unroll
        for (int i = 0; i < 16; i++)
            part[c2] = fmaf(ivl[i], wrow[i * 256], part[c2]);
    }
#pragma unroll
    for (int c2 = 0; c2 < NCLS; c2++) {
        float v = part[c2];
#pragma unroll
        for (int off = 32; off >= 1; off >>= 1) v += __shfl_down(v, off);
        if ((tid & 63) == 0) atomicAdd(&out[b * NCLS + c2], v * OUT_SCALE);
    }
    if (m == 0 && tid < NCLS) atomicAdd(&out[b * NCLS + tid], fcb[tid]);
}

extern "C" void kernel_launch(void* const* d_in, const int* in_sizes, int n_in,
                              void* d_out, int out_size, void* d_ws, size_t ws_size,
                              hipStream_t stream) {
    const float* x   = (const float*)d_in[0];
    const float* sre = (const float*)d_in[1];
    const float* sim = (const float*)d_in[2];
    const float* ph  = (const float*)d_in[3];
    const float* fcw = (const float*)d_in[4];
    const float* fcb = (const float*)d_in[5];
    float* out = (float*)d_out;

    hipMemsetAsync(out, 0, (size_t)(NB * NCLS) * sizeof(float), stream);
    donn_main<<<NM * NB, 256, 0, stream>>>(x, sre, sim, ph, fcw, fcb, out);
}